// Round 1
// baseline (103.425 us; speedup 1.0000x reference)
//
#include <hip/hip_runtime.h>
#include <hip/hip_bf16.h>

#define NROWS 8192
#define HALFN 4096
#define DIMK  128
#define JC    16              // j-chunks (grid dim)
#define LJ    (NROWS / JC)    // 512 columns per chunk
#define BAND  256             // rows per block in main kernel
#define NBAND (NROWS / BAND)  // 32

typedef __attribute__((ext_vector_type(8))) short short8;
typedef __attribute__((ext_vector_type(4))) float f32x4;

// exp(sim) = exp(2*dot) = 2^(dot * 2*log2(e))
#define EXPSCALE 2.8853900817779268f

static __device__ __forceinline__ float bf2f(unsigned short u) {
    union { float f; unsigned int i; } x;
    x.i = ((unsigned int)u) << 16;
    return x.f;
}

// ---------------- K1: normalize rows, write bf16 [8192][128] ----------------
__global__ __launch_bounds__(256) void k_norm(const float* __restrict__ zi,
                                              const float* __restrict__ zj,
                                              unsigned short* __restrict__ znb) {
    const int lane = threadIdx.x & 63;
    const int wave = threadIdx.x >> 6;
    const int row  = blockIdx.x * 4 + wave;
    const float* src = (row < HALFN) ? (zi + (size_t)row * DIMK)
                                     : (zj + (size_t)(row - HALFN) * DIMK);
    float2 v = *reinterpret_cast<const float2*>(src + lane * 2);
    float ss = v.x * v.x + v.y * v.y;
    #pragma unroll
    for (int m = 1; m < 64; m <<= 1) ss += __shfl_xor(ss, m);
    float rn = rsqrtf(ss);
    __hip_bfloat16 ha = __float2bfloat16(v.x * rn);
    __hip_bfloat16 hb = __float2bfloat16(v.y * rn);
    ushort2 o;
    o.x = *reinterpret_cast<unsigned short*>(&ha);
    o.y = *reinterpret_cast<unsigned short*>(&hb);
    *reinterpret_cast<ushort2*>(znb + (size_t)row * DIMK + lane * 2) = o;
}

// ---------------- K2: fused sim + exp row-sum (per j-chunk partials) --------
// grid = NBAND * JC blocks, 256 threads (4 waves). Each wave owns 64 rows
// (4 x 16-row MFMA fragments) and streams its chunk's 512 columns.
__global__ __launch_bounds__(256) void k_main(const unsigned short* __restrict__ znb,
                                              float* __restrict__ Spart) {
    const int lane = threadIdx.x & 63;
    const int wave = threadIdx.x >> 6;
    const int band = blockIdx.x & (NBAND - 1);
    const int jc   = blockIdx.x >> 5;   // / NBAND==32
    const int row0 = band * BAND + wave * 64;
    const int jbase = jc * LJ;

    const int rsel = lane & 15;   // fragment row/col selector
    const int g    = lane >> 4;   // k-group

    // A fragments: rows row0 .. row0+63, each lane: row = base + rsel,
    // k = kk*32 + g*8 .. +7 (8 contiguous bf16 = 16B load)
    short8 afr[4][4];
    #pragma unroll
    for (int rf = 0; rf < 4; ++rf)
        #pragma unroll
        for (int kk = 0; kk < 4; ++kk)
            afr[rf][kk] = *reinterpret_cast<const short8*>(
                znb + (size_t)(row0 + rf * 16 + rsel) * DIMK + kk * 32 + g * 8);

    float sacc[4][4];
    #pragma unroll
    for (int rf = 0; rf < 4; ++rf)
        #pragma unroll
        for (int r = 0; r < 4; ++r) sacc[rf][r] = 0.f;

    for (int jt = 0; jt < LJ / 16; ++jt) {
        const int j0 = jbase + jt * 16;
        short8 bfr[4];
        #pragma unroll
        for (int kk = 0; kk < 4; ++kk)
            bfr[kk] = *reinterpret_cast<const short8*>(
                znb + (size_t)(j0 + rsel) * DIMK + kk * 32 + g * 8);

        #pragma unroll
        for (int rf = 0; rf < 4; ++rf) {
            f32x4 c = {0.f, 0.f, 0.f, 0.f};
            #pragma unroll
            for (int kk = 0; kk < 4; ++kk)
                c = __builtin_amdgcn_mfma_f32_16x16x32_bf16(afr[rf][kk], bfr[kk], c, 0, 0, 0);
            // C layout (m89): col = lane&15, row = (lane>>4)*4 + reg
            const bool isdiag = (j0 == row0 + rf * 16);
            if (__builtin_expect(isdiag, 0)) {
                #pragma unroll
                for (int r = 0; r < 4; ++r) {
                    float e = exp2f(c[r] * EXPSCALE);
                    if (rsel == g * 4 + r) e = 0.f;   // mask j == i
                    sacc[rf][r] += e;
                }
            } else {
                #pragma unroll
                for (int r = 0; r < 4; ++r)
                    sacc[rf][r] += exp2f(c[r] * EXPSCALE);
            }
        }
    }

    // Reduce over the 16 lanes of each k-group (they hold the 16 columns
    // of the same 4 rows); xor masks < 16 stay within the group.
    #pragma unroll
    for (int rf = 0; rf < 4; ++rf)
        #pragma unroll
        for (int r = 0; r < 4; ++r) {
            float v = sacc[rf][r];
            v += __shfl_xor(v, 1);
            v += __shfl_xor(v, 2);
            v += __shfl_xor(v, 4);
            v += __shfl_xor(v, 8);
            sacc[rf][r] = v;
        }
    if (rsel == 0) {
        #pragma unroll
        for (int rf = 0; rf < 4; ++rf) {
            float4 o = make_float4(sacc[rf][0], sacc[rf][1], sacc[rf][2], sacc[rf][3]);
            *reinterpret_cast<float4*>(Spart + (size_t)jc * NROWS + row0 + rf * 16 + g * 4) = o;
        }
    }
}

// ---------------- K3: per-row  log(S) - pos  --------------------------------
__global__ __launch_bounds__(256) void k_rowterm(const unsigned short* __restrict__ znb,
                                                 const float* __restrict__ Spart,
                                                 float* __restrict__ terms) {
    const int lane = threadIdx.x & 63;
    const int wave = threadIdx.x >> 6;
    const int row  = blockIdx.x * 4 + wave;
    const int p    = (row + HALFN) & (NROWS - 1);

    ushort2 a = *reinterpret_cast<const ushort2*>(znb + (size_t)row * DIMK + lane * 2);
    ushort2 b = *reinterpret_cast<const ushort2*>(znb + (size_t)p   * DIMK + lane * 2);
    float d = bf2f(a.x) * bf2f(b.x) + bf2f(a.y) * bf2f(b.y);
    float S = (lane < JC) ? Spart[(size_t)lane * NROWS + row] : 0.f;
    #pragma unroll
    for (int m = 1; m < 64; m <<= 1) {
        d += __shfl_xor(d, m);
        S += __shfl_xor(S, m);
    }
    if (lane == 0) terms[row] = __logf(S) - 2.0f * d;
}

// ---------------- K4: final reduce -> loss ----------------------------------
__global__ __launch_bounds__(1024) void k_final(const float* __restrict__ terms,
                                                float* __restrict__ out) {
    __shared__ float red[16];
    const int tid = threadIdx.x;
    float s = 0.f;
    for (int k = tid; k < NROWS; k += 1024) s += terms[k];
    #pragma unroll
    for (int m = 1; m < 64; m <<= 1) s += __shfl_xor(s, m);
    if ((tid & 63) == 0) red[tid >> 6] = s;
    __syncthreads();
    if (tid < 64) {
        float v = (tid < 16) ? red[tid] : 0.f;
        #pragma unroll
        for (int m = 1; m < 16; m <<= 1) v += __shfl_xor(v, m);
        if (tid == 0) out[0] = v * (1.0f / (float)NROWS);
    }
}

extern "C" void kernel_launch(void* const* d_in, const int* in_sizes, int n_in,
                              void* d_out, int out_size, void* d_ws, size_t ws_size,
                              hipStream_t stream) {
    const float* zi = (const float*)d_in[0];
    const float* zj = (const float*)d_in[1];
    float* out = (float*)d_out;
    char* ws = (char*)d_ws;

    unsigned short* znb  = (unsigned short*)ws;                         // 2 MB
    float*         Spart = (float*)(ws + (size_t)NROWS * DIMK * 2);     // 512 KB
    float*         terms = (float*)(ws + (size_t)NROWS * DIMK * 2
                                       + (size_t)JC * NROWS * 4);       // 32 KB

    k_norm   <<<NROWS / 4, 256, 0, stream>>>(zi, zj, znb);
    k_main   <<<NBAND * JC, 256, 0, stream>>>(znb, Spart);
    k_rowterm<<<NROWS / 4, 256, 0, stream>>>(znb, Spart, terms);
    k_final  <<<1, 1024, 0, stream>>>(terms, out);
}